// Round 3
// baseline (6615.463 us; speedup 1.0000x reference)
//
#include <hip/hip_runtime.h>
#include <math.h>

#define DIM 4096
#define RDIM 16
#define RIDGE 1e-5f
#define NCHUNK 8    // buildA m-chunks (512 rows each)
#define NPK 136     // packed upper-tri size
#define TSLICE 16   // tpart slices
#define SSLICE 8    // spsi slices

__device__ __forceinline__ int pidx(int r, int s) { return r * (31 - r) / 2 + s; } // r<=s

__device__ __forceinline__ float alpha_of(float cl) {
    return cl * (1.f - erff(sqrtf(cl))) +
           0.5f * (erff(cl * 0.70710678118f) -
                   0.79788456080f * cl * expf(-0.5f * cl * cl));
}

// ---------------- transpose X -> Xt (Xt lives in d_out until final GEMM) ----
__global__ void __launch_bounds__(256) k_transpose(const float* __restrict__ X,
                                                   float* __restrict__ Xt) {
    __shared__ float tile[64][65];
    int bx = blockIdx.x, by = blockIdx.y;
    int lx = threadIdx.x & 63;
    int ly = threadIdx.x >> 6;
#pragma unroll
    for (int i = 0; i < 16; ++i) {
        int r = ly + i * 4;
        tile[r][lx] = X[(size_t)(by * 64 + r) * DIM + bx * 64 + lx];
    }
    __syncthreads();
#pragma unroll
    for (int i = 0; i < 16; ++i) {
        int r = ly + i * 4;
        Xt[(size_t)(bx * 64 + r) * DIM + by * 64 + lx] = tile[lx][r];
    }
}

// ---------------- observed-count per column -------------------------------
__global__ void __launch_bounds__(256) k_count(const float* __restrict__ Xp,
                                               float* __restrict__ cnt) {
    int c = blockIdx.x * 256 + threadIdx.x;
    int m0 = blockIdx.y * 256;
    float acc = 0.f;
    for (int m = 0; m < 256; ++m) {
        float x = Xp[(size_t)(m0 + m) * DIM + c];
        acc += (x != 0.f) ? 1.f : 0.f;
    }
    atomicAdd(&cnt[c], acc);
}

// ---------------- init copies ----------------------------------------------
__global__ void k_init_uc(const float* __restrict__ U, float* __restrict__ Uc) {
    int i = blockIdx.x * 256 + threadIdx.x;
    ((float4*)Uc)[i] = ((const float4*)U)[i];
}
__global__ void k_init_vt(const float* __restrict__ V, float* __restrict__ Vtb) {
    int n = blockIdx.x * 256 + threadIdx.x;
#pragma unroll
    for (int r = 0; r < RDIM; ++r) Vtb[(size_t)n * RDIM + r] = V[(size_t)r * DIM + n];
}

// ---------------- A partials, packed upper-tri -----------------------------
// block 256 thr: g = tid&15 (4 cols), j = tid>>4 (A row). grid (64, NCHUNK).
__global__ void __launch_bounds__(256) k_buildA(const float* __restrict__ Xp,
                                                const float* __restrict__ D,
                                                float* __restrict__ Apart) {
    __shared__ float ds[128 * RDIM];
    const int g = threadIdx.x & 15;
    const int j = threadIdx.x >> 4;
    const int cbase = blockIdx.x * 64 + g * 4;
    const int m0 = blockIdx.y * 512;

    float a[4][16];
#pragma unroll
    for (int i = 0; i < 4; ++i)
#pragma unroll
        for (int s = 0; s < 16; ++s) a[i][s] = 0.f;

    for (int sub = 0; sub < 4; ++sub) {
        const float* Dsub = D + (size_t)(m0 + sub * 128) * RDIM;
        ((float4*)ds)[threadIdx.x]       = ((const float4*)Dsub)[threadIdx.x];
        ((float4*)ds)[256 + threadIdx.x] = ((const float4*)Dsub)[256 + threadIdx.x];
        __syncthreads();

        for (int m = 0; m < 128; ++m) {
            float4 x4 = *(const float4*)(Xp + (size_t)(m0 + sub * 128 + m) * DIM + cbase);
            float u[16];
#pragma unroll
            for (int q = 0; q < 4; ++q) {
                float4 u4 = ((const float4*)(ds + m * RDIM))[q];
                u[q * 4 + 0] = u4.x; u[q * 4 + 1] = u4.y;
                u[q * 4 + 2] = u4.z; u[q * 4 + 3] = u4.w;
            }
            float uj = ds[m * RDIM + j];
            float p0 = (x4.x != 0.f) ? uj : 0.f;
            float p1 = (x4.y != 0.f) ? uj : 0.f;
            float p2 = (x4.z != 0.f) ? uj : 0.f;
            float p3 = (x4.w != 0.f) ? uj : 0.f;
#pragma unroll
            for (int s = 0; s < 16; ++s) {
                a[0][s] += p0 * u[s];
                a[1][s] += p1 * u[s];
                a[2][s] += p2 * u[s];
                a[3][s] += p3 * u[s];
            }
        }
        __syncthreads();
    }
    // packed store: only s >= j
#pragma unroll
    for (int i = 0; i < 4; ++i) {
        size_t base = ((size_t)blockIdx.y * DIM + (cbase + i)) * NPK + (size_t)j * (31 - j) / 2;
        for (int s = j; s < 16; ++s) Apart[base + s] = a[i][s];
    }
}

// ------- reduce packed chunks, invert 16x16 SPD, zero spsi -----------------
// block 128 thr (8 matrices), grid 512.
__global__ void __launch_bounds__(128) k_invert(const float* __restrict__ Apart,
                                                float* __restrict__ Ainv,
                                                float* __restrict__ spsi) {
    int gt = blockIdx.x * 128 + threadIdx.x;
    int c = gt >> 4;
    int j = gt & 15;

    float a[16], b[16];
#pragma unroll
    for (int s = 0; s < 16; ++s) {
        int r0 = j < s ? j : s;
        int s0 = j < s ? s : j;
        int off = pidx(r0, s0);
        float acc = 0.f;
#pragma unroll
        for (int ch = 0; ch < NCHUNK; ++ch)
            acc += Apart[((size_t)ch * DIM + c) * NPK + off];
        a[s] = acc;
        b[s] = 0.f;
    }
    a[j] += RIDGE;
    b[j] = 1.f;

#pragma unroll
    for (int k = 0; k < RDIM; ++k) {
        float pivA[16], pivB[16];
#pragma unroll
        for (int s = 0; s < 16; ++s) {
            pivA[s] = __shfl(a[s], k, 16);
            pivB[s] = __shfl(b[s], k, 16);
        }
        float pinv = 1.f / pivA[k];
        float f = a[k];
        if (j == k) {
#pragma unroll
            for (int s = 0; s < 16; ++s) { a[s] = pivA[s] * pinv; b[s] = pivB[s] * pinv; }
        } else {
#pragma unroll
            for (int s = 0; s < 16; ++s) {
                a[s] -= f * pinv * pivA[s];
                b[s] -= f * pinv * pivB[s];
            }
        }
    }
#pragma unroll
    for (int s = 0; s < 16; ++s) Ainv[(size_t)c * 256 + j * 16 + s] = b[s];
    spsi[gt] = 0.f;   // zero both iteration slices (2*8*4096 == 512*128 threads)
}

// ---- inline sigma helper: sum 8 slices of spsi, tau formula ---------------
__device__ __forceinline__ float sig_from_spsi(const float* spsi, const float* cnt,
                                               int c, float alpha, float ll) {
    float s = 0.f;
#pragma unroll
    for (int sl = 0; sl < SSLICE; ++sl) s += spsi[sl * DIM + c];
    return ll * sqrtf(s) * rsqrtf(2.f * cnt[c] * alpha);
}

// ---------------- pass 1: column sums of psi^2 (T=4 cols/thread) -----------
template <int ROWS>
__global__ void __launch_bounds__(256) k_it_a(const float* __restrict__ Xp,
                                              const float* __restrict__ D,
                                              const float* __restrict__ B,
                                              const float* __restrict__ spsi_prev,
                                              const float* __restrict__ sigma,
                                              const float* __restrict__ cnt,
                                              const float* __restrict__ cvec,
                                              const float* __restrict__ lvec,
                                              int layer, int use_s0,
                                              float* __restrict__ spsi_out) {
    __shared__ float ds[ROWS * RDIM];
    const int c = blockIdx.x * 1024 + threadIdx.x * 4;
    const int m0 = blockIdx.y * ROWS;
    constexpr int NV = ROWS * RDIM / 4;
    for (int i = threadIdx.x; i < NV; i += 256)
        ((float4*)ds)[i] = ((const float4*)(D + (size_t)m0 * RDIM))[i];

    float cl = cvec[layer], ll = lvec[layer];
    float al = alpha_of(cl);
    float beta[4][16], invsg[4];
#pragma unroll
    for (int i = 0; i < 4; ++i) {
#pragma unroll
        for (int q = 0; q < 4; ++q) {
            float4 t4 = ((const float4*)(B + (size_t)(c + i) * RDIM))[q];
            beta[i][q * 4 + 0] = t4.x; beta[i][q * 4 + 1] = t4.y;
            beta[i][q * 4 + 2] = t4.z; beta[i][q * 4 + 3] = t4.w;
        }
        float sg = use_s0 ? sigma[0] : sig_from_spsi(spsi_prev, cnt, c + i, al, ll);
        invsg[i] = 1.f / sg;
    }
    __syncthreads();

    float acc[4] = {0.f, 0.f, 0.f, 0.f};
    for (int m = 0; m < ROWS; ++m) {
        float u[16];
#pragma unroll
        for (int q = 0; q < 4; ++q) {
            float4 u4 = ((const float4*)(ds + m * RDIM))[q];
            u[q * 4 + 0] = u4.x; u[q * 4 + 1] = u4.y;
            u[q * 4 + 2] = u4.z; u[q * 4 + 3] = u4.w;
        }
        float4 x4 = *(const float4*)(Xp + (size_t)(m0 + m) * DIM + c);
        float xv[4] = {x4.x, x4.y, x4.z, x4.w};
#pragma unroll
        for (int i = 0; i < 4; ++i) {
            float dot = 0.f;
#pragma unroll
            for (int s = 0; s < 16; ++s) dot += u[s] * beta[i][s];
            float res = (xv[i] != 0.f) ? (xv[i] - dot) : 0.f;
            float psi = fminf(fmaxf(res * invsg[i], -cl), cl);
            acc[i] += psi * psi;
        }
    }
    float* outsl = spsi_out + (blockIdx.y & (SSLICE - 1)) * DIM;
#pragma unroll
    for (int i = 0; i < 4; ++i) atomicAdd(&outsl[c + i], acc[i]);
}

// ---------------- pass 2: t partials (sigma inline from spsi) --------------
template <int ROWS>
__global__ void __launch_bounds__(256) k_it_c(const float* __restrict__ Xp,
                                              const float* __restrict__ D,
                                              const float* __restrict__ B,
                                              const float* __restrict__ spsi_sig,
                                              const float* __restrict__ cnt,
                                              const float* __restrict__ cvec,
                                              const float* __restrict__ lvec,
                                              int layer,
                                              float* __restrict__ tpart) {
    __shared__ float ds[ROWS * RDIM];
    const int c = blockIdx.x * 1024 + threadIdx.x * 4;
    const int m0 = blockIdx.y * ROWS;
    constexpr int NV = ROWS * RDIM / 4;
    for (int i = threadIdx.x; i < NV; i += 256)
        ((float4*)ds)[i] = ((const float4*)(D + (size_t)m0 * RDIM))[i];

    float cl = cvec[layer], ll = lvec[layer];
    float al = alpha_of(cl);
    float beta[4][16], sg[4], invsg[4];
#pragma unroll
    for (int i = 0; i < 4; ++i) {
#pragma unroll
        for (int q = 0; q < 4; ++q) {
            float4 t4 = ((const float4*)(B + (size_t)(c + i) * RDIM))[q];
            beta[i][q * 4 + 0] = t4.x; beta[i][q * 4 + 1] = t4.y;
            beta[i][q * 4 + 2] = t4.z; beta[i][q * 4 + 3] = t4.w;
        }
        sg[i] = sig_from_spsi(spsi_sig, cnt, c + i, al, ll);
        invsg[i] = 1.f / sg[i];
    }
    __syncthreads();

    float tac[4][16];
#pragma unroll
    for (int i = 0; i < 4; ++i)
#pragma unroll
        for (int s = 0; s < 16; ++s) tac[i][s] = 0.f;

    for (int m = 0; m < ROWS; ++m) {
        float u[16];
#pragma unroll
        for (int q = 0; q < 4; ++q) {
            float4 u4 = ((const float4*)(ds + m * RDIM))[q];
            u[q * 4 + 0] = u4.x; u[q * 4 + 1] = u4.y;
            u[q * 4 + 2] = u4.z; u[q * 4 + 3] = u4.w;
        }
        float4 x4 = *(const float4*)(Xp + (size_t)(m0 + m) * DIM + c);
        float xv[4] = {x4.x, x4.y, x4.z, x4.w};
#pragma unroll
        for (int i = 0; i < 4; ++i) {
            float dot = 0.f;
#pragma unroll
            for (int s = 0; s < 16; ++s) dot += u[s] * beta[i][s];
            float res = (xv[i] != 0.f) ? (xv[i] - dot) : 0.f;
            float psi2 = fminf(fmaxf(res * invsg[i], -cl), cl);
            float coeff = psi2 * sg[i];
#pragma unroll
            for (int s = 0; s < 16; ++s) tac[i][s] += u[s] * coeff;
        }
    }
    float* tsl = tpart + (size_t)(blockIdx.y & (TSLICE - 1)) * DIM * RDIM;
#pragma unroll
    for (int i = 0; i < 4; ++i)
#pragma unroll
        for (int s = 0; s < 16; ++s)
            atomicAdd(&tsl[(size_t)(c + i) * RDIM + s], tac[i][s]);
}

// ------- beta update: B += mu * Ainv @ t ; zero tpart after use ------------
// block 256 thr (16 matrices), grid 256.
__global__ void __launch_bounds__(256) k_it_d(const float* __restrict__ Ainv,
                                              float* __restrict__ tpart,
                                              const float* __restrict__ mvec, int layer,
                                              float* __restrict__ B) {
    __shared__ float t_sh[16][16];
    int c0 = blockIdx.x * 16;
    int cl_ = threadIdx.x >> 4;
    int s = threadIdx.x & 15;
    float tv = 0.f;
#pragma unroll
    for (int sl = 0; sl < TSLICE; ++sl)
        tv += tpart[((size_t)sl * DIM + c0 + cl_) * RDIM + s];
    t_sh[cl_][s] = tv;
#pragma unroll
    for (int sl = 0; sl < TSLICE; ++sl)
        tpart[((size_t)sl * DIM + c0 + cl_) * RDIM + s] = 0.f;
    __syncthreads();

    int c = c0 + cl_;
    int j = s;  // reinterpret: thread = (matrix cl_, row j)
    float ml = mvec[layer];
    float d = 0.f;
#pragma unroll
    for (int q = 0; q < 4; ++q) {
        float4 a4 = *(const float4*)(Ainv + (size_t)c * 256 + j * 16 + q * 4);
        d += a4.x * t_sh[cl_][q * 4 + 0] + a4.y * t_sh[cl_][q * 4 + 1] +
             a4.z * t_sh[cl_][q * 4 + 2] + a4.w * t_sh[cl_][q * 4 + 3];
    }
    B[(size_t)c * RDIM + j] += ml * d;
}

// ---------------- final out = Uc @ Vtb^T -----------------------------------
__global__ void __launch_bounds__(256) k_out(const float* __restrict__ Uc,
                                             const float* __restrict__ Vtb,
                                             float* __restrict__ out) {
    __shared__ float us[64 * RDIM];
    int j = blockIdx.x * 256 + threadIdx.x;
    int i0 = blockIdx.y * 64;
    ((float4*)us)[threadIdx.x] = ((const float4*)(Uc + (size_t)i0 * RDIM))[threadIdx.x];
    float beta[16];
#pragma unroll
    for (int q = 0; q < 4; ++q) {
        float4 t4 = ((const float4*)(Vtb + (size_t)j * RDIM))[q];
        beta[q * 4 + 0] = t4.x; beta[q * 4 + 1] = t4.y;
        beta[q * 4 + 2] = t4.z; beta[q * 4 + 3] = t4.w;
    }
    __syncthreads();
#pragma unroll 4
    for (int r = 0; r < 64; ++r) {
        float dot = 0.f;
#pragma unroll
        for (int q = 0; q < 4; ++q) {
            float4 u4 = ((const float4*)(us + r * RDIM))[q];
            dot += u4.x * beta[q * 4 + 0] + u4.y * beta[q * 4 + 1] +
                   u4.z * beta[q * 4 + 2] + u4.w * beta[q * 4 + 3];
        }
        out[(size_t)(i0 + r) * DIM + j] = dot;
    }
}

extern "C" void kernel_launch(void* const* d_in, const int* in_sizes, int n_in,
                              void* d_out, int out_size, void* d_ws, size_t ws_size,
                              hipStream_t stream) {
    const float* U = (const float*)d_in[0];
    const float* V = (const float*)d_in[1];
    const float* X = (const float*)d_in[2];
    const float* cvec = (const float*)d_in[3];
    const float* lvec = (const float*)d_in[4];
    const float* mvec = (const float*)d_in[5];
    const float* sigma = (const float*)d_in[6];
    float* out = (float*)d_out;

    float* ws = (float*)d_ws;
    float* Apart = ws;                                    // 8*4096*136
    float* tpart = Apart + (size_t)NCHUNK * DIM * NPK;    // 16*4096*16
    float* spsi  = tpart + (size_t)TSLICE * DIM * RDIM;   // 2*8*4096
    float* cntc  = spsi + 2 * SSLICE * DIM;               // 4096
    float* cntr  = cntc + DIM;                            // 4096
    float* Uc    = cntr + DIM;                            // 4096*16
    float* Vtb   = Uc + (size_t)DIM * RDIM;               // 4096*16
    float* Ainv  = Vtb + (size_t)DIM * RDIM;              // 4096*256
    float* Xt    = out;  // reuse d_out as transpose scratch until k_out

    float* spsi0 = spsi;
    float* spsi1 = spsi + SSLICE * DIM;

    // zero tpart, spsi, cntc, cntr (contiguous)
    hipMemsetAsync(tpart, 0,
                   ((size_t)TSLICE * DIM * RDIM + 2 * SSLICE * DIM + 2 * DIM) * sizeof(float),
                   stream);

    k_transpose<<<dim3(64, 64), 256, 0, stream>>>(X, Xt);
    k_init_uc<<<64, 256, 0, stream>>>(U, Uc);
    k_init_vt<<<16, 256, 0, stream>>>(V, Vtb);
    k_count<<<dim3(16, 16), 256, 0, stream>>>(X, cntc);
    k_count<<<dim3(16, 16), 256, 0, stream>>>(Xt, cntr);

    for (int layer = 0; layer < 3; ++layer) {
        // ---- V step: columns of X, design rows = Uc, beta rows = Vtb ----
        k_buildA<<<dim3(64, NCHUNK), 256, 0, stream>>>(X, Uc, Apart);
        k_invert<<<512, 128, 0, stream>>>(Apart, Ainv, spsi);
        k_it_a<32><<<dim3(4, 128), 256, 0, stream>>>(X, Uc, Vtb, spsi0, sigma, cntc,
                                                     cvec, lvec, layer, 1, spsi0);
        k_it_c<32><<<dim3(4, 128), 256, 0, stream>>>(X, Uc, Vtb, spsi0, cntc,
                                                     cvec, lvec, layer, tpart);
        k_it_d<<<256, 256, 0, stream>>>(Ainv, tpart, mvec, layer, Vtb);
        k_it_a<32><<<dim3(4, 128), 256, 0, stream>>>(X, Uc, Vtb, spsi0, sigma, cntc,
                                                     cvec, lvec, layer, 0, spsi1);
        k_it_c<32><<<dim3(4, 128), 256, 0, stream>>>(X, Uc, Vtb, spsi1, cntc,
                                                     cvec, lvec, layer, tpart);
        k_it_d<<<256, 256, 0, stream>>>(Ainv, tpart, mvec, layer, Vtb);

        // ---- U step: columns of Xt, design rows = Vtb, beta rows = Uc ----
        k_buildA<<<dim3(64, NCHUNK), 256, 0, stream>>>(Xt, Vtb, Apart);
        k_invert<<<512, 128, 0, stream>>>(Apart, Ainv, spsi);
        k_it_a<32><<<dim3(4, 128), 256, 0, stream>>>(Xt, Vtb, Uc, spsi0, sigma, cntr,
                                                     cvec, lvec, layer, 1, spsi0);
        k_it_c<32><<<dim3(4, 128), 256, 0, stream>>>(Xt, Vtb, Uc, spsi0, cntr,
                                                     cvec, lvec, layer, tpart);
        k_it_d<<<256, 256, 0, stream>>>(Ainv, tpart, mvec, layer, Uc);
        k_it_a<32><<<dim3(4, 128), 256, 0, stream>>>(Xt, Vtb, Uc, spsi0, sigma, cntr,
                                                     cvec, lvec, layer, 0, spsi1);
        k_it_c<32><<<dim3(4, 128), 256, 0, stream>>>(Xt, Vtb, Uc, spsi1, cntr,
                                                     cvec, lvec, layer, tpart);
        k_it_d<<<256, 256, 0, stream>>>(Ainv, tpart, mvec, layer, Uc);
    }
    k_out<<<dim3(16, 64), 256, 0, stream>>>(Uc, Vtb, out);
}

// Round 4
// 2081.339 us; speedup vs baseline: 3.1785x; 3.1785x over previous
//
#include <hip/hip_runtime.h>
#include <math.h>

#define DIM 4096
#define RDIM 16
#define RIDGE 1e-5f
#define NCHUNK 16   // buildA m-chunks (256 rows each)
#define NPK 136     // packed upper-tri size
#define NSL 128     // streaming partial slices (= grid.y of it_a/it_c)
#define SROWS 32    // rows per streaming block (NSL*SROWS == DIM)

__device__ __forceinline__ int pidx(int r, int s) { return r * (31 - r) / 2 + s; } // r<=s

__device__ __forceinline__ float alpha_of(float cl) {
    return cl * (1.f - erff(sqrtf(cl))) +
           0.5f * (erff(cl * 0.70710678118f) -
                   0.79788456080f * cl * expf(-0.5f * cl * cl));
}

// ---------------- transpose X -> Xt (Xt lives in d_out until final GEMM) ----
__global__ void __launch_bounds__(256) k_transpose(const float* __restrict__ X,
                                                   float* __restrict__ Xt) {
    __shared__ float tile[64][65];
    int bx = blockIdx.x, by = blockIdx.y;
    int lx = threadIdx.x & 63;
    int ly = threadIdx.x >> 6;
#pragma unroll
    for (int i = 0; i < 16; ++i) {
        int r = ly + i * 4;
        tile[r][lx] = X[(size_t)(by * 64 + r) * DIM + bx * 64 + lx];
    }
    __syncthreads();
#pragma unroll
    for (int i = 0; i < 16; ++i) {
        int r = ly + i * 4;
        Xt[(size_t)(bx * 64 + r) * DIM + by * 64 + lx] = tile[lx][r];
    }
}

// ---------------- observed-count per column (setup only, atomics OK) -------
__global__ void __launch_bounds__(256) k_count(const float* __restrict__ Xp,
                                               float* __restrict__ cnt) {
    int c = blockIdx.x * 256 + threadIdx.x;
    int m0 = blockIdx.y * 256;
    float acc = 0.f;
    for (int m = 0; m < 256; ++m) {
        float x = Xp[(size_t)(m0 + m) * DIM + c];
        acc += (x != 0.f) ? 1.f : 0.f;
    }
    atomicAdd(&cnt[c], acc);
}

// ---------------- init copies ----------------------------------------------
__global__ void k_init_uc(const float* __restrict__ U, float* __restrict__ Uc) {
    int i = blockIdx.x * 256 + threadIdx.x;
    ((float4*)Uc)[i] = ((const float4*)U)[i];
}
__global__ void k_init_vt(const float* __restrict__ V, float* __restrict__ Vtb) {
    int n = blockIdx.x * 256 + threadIdx.x;
#pragma unroll
    for (int r = 0; r < RDIM; ++r) Vtb[(size_t)n * RDIM + r] = V[(size_t)r * DIM + n];
}

// ---------------- A partials, packed upper-tri, plain stores ---------------
// block 256 thr: g = tid&15 (4 cols), j = tid>>4 (A row). grid (64, NCHUNK).
__global__ void __launch_bounds__(256) k_buildA(const float* __restrict__ Xp,
                                                const float* __restrict__ D,
                                                float* __restrict__ Apart) {
    __shared__ float ds[128 * RDIM];
    const int g = threadIdx.x & 15;
    const int j = threadIdx.x >> 4;
    const int cbase = blockIdx.x * 64 + g * 4;
    const int m0 = blockIdx.y * 256;

    float a[4][16];
#pragma unroll
    for (int i = 0; i < 4; ++i)
#pragma unroll
        for (int s = 0; s < 16; ++s) a[i][s] = 0.f;

    for (int sub = 0; sub < 2; ++sub) {
        const float* Dsub = D + (size_t)(m0 + sub * 128) * RDIM;
        ((float4*)ds)[threadIdx.x]       = ((const float4*)Dsub)[threadIdx.x];
        ((float4*)ds)[256 + threadIdx.x] = ((const float4*)Dsub)[256 + threadIdx.x];
        __syncthreads();

        for (int m = 0; m < 128; ++m) {
            float4 x4 = *(const float4*)(Xp + (size_t)(m0 + sub * 128 + m) * DIM + cbase);
            float u[16];
#pragma unroll
            for (int q = 0; q < 4; ++q) {
                float4 u4 = ((const float4*)(ds + m * RDIM))[q];
                u[q * 4 + 0] = u4.x; u[q * 4 + 1] = u4.y;
                u[q * 4 + 2] = u4.z; u[q * 4 + 3] = u4.w;
            }
            float uj = ds[m * RDIM + j];
            float p0 = (x4.x != 0.f) ? uj : 0.f;
            float p1 = (x4.y != 0.f) ? uj : 0.f;
            float p2 = (x4.z != 0.f) ? uj : 0.f;
            float p3 = (x4.w != 0.f) ? uj : 0.f;
#pragma unroll
            for (int s = 0; s < 16; ++s) {
                a[0][s] += p0 * u[s];
                a[1][s] += p1 * u[s];
                a[2][s] += p2 * u[s];
                a[3][s] += p3 * u[s];
            }
        }
        __syncthreads();
    }
    // packed store, unrolled + predicated (no dynamic register indexing)
#pragma unroll
    for (int i = 0; i < 4; ++i) {
        size_t base = ((size_t)blockIdx.y * DIM + (cbase + i)) * NPK + (size_t)j * (31 - j) / 2;
#pragma unroll
        for (int s = 0; s < 16; ++s)
            if (s >= j) Apart[base + s] = a[i][s];
    }
}

// ------- reduce packed chunks, invert 16x16 SPD ----------------------------
// block 128 thr (8 matrices), grid 512.
__global__ void __launch_bounds__(128) k_invert(const float* __restrict__ Apart,
                                                float* __restrict__ Ainv) {
    int gt = blockIdx.x * 128 + threadIdx.x;
    int c = gt >> 4;
    int j = gt & 15;

    float a[16], b[16];
#pragma unroll
    for (int s = 0; s < 16; ++s) {
        int r0 = j < s ? j : s;
        int s0 = j < s ? s : j;
        int off = pidx(r0, s0);
        float acc = 0.f;
#pragma unroll
        for (int ch = 0; ch < NCHUNK; ++ch)
            acc += Apart[((size_t)ch * DIM + c) * NPK + off];
        a[s] = acc;
        b[s] = 0.f;
    }
    a[j] += RIDGE;
    b[j] = 1.f;

#pragma unroll
    for (int k = 0; k < RDIM; ++k) {
        float pivA[16], pivB[16];
#pragma unroll
        for (int s = 0; s < 16; ++s) {
            pivA[s] = __shfl(a[s], k, 16);
            pivB[s] = __shfl(b[s], k, 16);
        }
        float pinv = 1.f / pivA[k];
        float f = a[k];
        if (j == k) {
#pragma unroll
            for (int s = 0; s < 16; ++s) { a[s] = pivA[s] * pinv; b[s] = pivB[s] * pinv; }
        } else {
#pragma unroll
            for (int s = 0; s < 16; ++s) {
                a[s] -= f * pinv * pivA[s];
                b[s] -= f * pinv * pivB[s];
            }
        }
    }
#pragma unroll
    for (int s = 0; s < 16; ++s) Ainv[(size_t)c * 256 + j * 16 + s] = b[s];
}

// ---- inline sigma: sum NSL slices of spart (float4 over 4 cols) -----------
__device__ __forceinline__ float4 sig4_from_spart(const float* __restrict__ spart,
                                                  const float* __restrict__ cnt,
                                                  int c, float alpha, float ll) {
    float4 ssum = make_float4(0.f, 0.f, 0.f, 0.f);
#pragma unroll 8
    for (int sl = 0; sl < NSL; ++sl) {
        float4 v = *(const float4*)(spart + (size_t)sl * DIM + c);
        ssum.x += v.x; ssum.y += v.y; ssum.z += v.z; ssum.w += v.w;
    }
    float4 cn = *(const float4*)(cnt + c);
    float4 sg;
    sg.x = ll * sqrtf(ssum.x) * rsqrtf(2.f * cn.x * alpha);
    sg.y = ll * sqrtf(ssum.y) * rsqrtf(2.f * cn.y * alpha);
    sg.z = ll * sqrtf(ssum.z) * rsqrtf(2.f * cn.z * alpha);
    sg.w = ll * sqrtf(ssum.w) * rsqrtf(2.f * cn.w * alpha);
    return sg;
}

// ---------------- pass 1: slice-partial column sums of psi^2 ---------------
// grid (4, NSL), block 256, 4 cols/thread, SROWS rows/slice. Plain stores.
__global__ void __launch_bounds__(256) k_it_a(const float* __restrict__ Xp,
                                              const float* __restrict__ D,
                                              const float* __restrict__ B,
                                              const float* __restrict__ spart_prev,
                                              const float* __restrict__ sigma,
                                              const float* __restrict__ cnt,
                                              const float* __restrict__ cvec,
                                              const float* __restrict__ lvec,
                                              int layer, int use_s0,
                                              float* __restrict__ spart_out) {
    __shared__ float ds[SROWS * RDIM];
    const int c = blockIdx.x * 1024 + threadIdx.x * 4;
    const int m0 = blockIdx.y * SROWS;
    if (threadIdx.x < SROWS * RDIM / 4)
        ((float4*)ds)[threadIdx.x] = ((const float4*)(D + (size_t)m0 * RDIM))[threadIdx.x];

    float cl = cvec[layer], ll = lvec[layer];
    float al = alpha_of(cl);
    float4 sg4;
    if (use_s0) {
        float s0 = sigma[0];
        sg4 = make_float4(s0, s0, s0, s0);
    } else {
        sg4 = sig4_from_spart(spart_prev, cnt, c, al, ll);
    }
    float invsg[4] = {1.f / sg4.x, 1.f / sg4.y, 1.f / sg4.z, 1.f / sg4.w};

    float beta[4][16];
#pragma unroll
    for (int i = 0; i < 4; ++i)
#pragma unroll
        for (int q = 0; q < 4; ++q) {
            float4 t4 = ((const float4*)(B + (size_t)(c + i) * RDIM))[q];
            beta[i][q * 4 + 0] = t4.x; beta[i][q * 4 + 1] = t4.y;
            beta[i][q * 4 + 2] = t4.z; beta[i][q * 4 + 3] = t4.w;
        }
    __syncthreads();

    float acc[4] = {0.f, 0.f, 0.f, 0.f};
    for (int m = 0; m < SROWS; ++m) {
        float u[16];
#pragma unroll
        for (int q = 0; q < 4; ++q) {
            float4 u4 = ((const float4*)(ds + m * RDIM))[q];
            u[q * 4 + 0] = u4.x; u[q * 4 + 1] = u4.y;
            u[q * 4 + 2] = u4.z; u[q * 4 + 3] = u4.w;
        }
        float4 x4 = *(const float4*)(Xp + (size_t)(m0 + m) * DIM + c);
        float xv[4] = {x4.x, x4.y, x4.z, x4.w};
#pragma unroll
        for (int i = 0; i < 4; ++i) {
            float dot = 0.f;
#pragma unroll
            for (int s = 0; s < 16; ++s) dot += u[s] * beta[i][s];
            float res = (xv[i] != 0.f) ? (xv[i] - dot) : 0.f;
            float psi = fminf(fmaxf(res * invsg[i], -cl), cl);
            acc[i] += psi * psi;
        }
    }
    *(float4*)(spart_out + (size_t)blockIdx.y * DIM + c) =
        make_float4(acc[0], acc[1], acc[2], acc[3]);
}

// ---------------- pass 2: slice-partial t, plain stores --------------------
__global__ void __launch_bounds__(256) k_it_c(const float* __restrict__ Xp,
                                              const float* __restrict__ D,
                                              const float* __restrict__ B,
                                              const float* __restrict__ spart_sig,
                                              const float* __restrict__ cnt,
                                              const float* __restrict__ cvec,
                                              const float* __restrict__ lvec,
                                              int layer,
                                              float* __restrict__ tpart) {
    __shared__ float ds[SROWS * RDIM];
    const int c = blockIdx.x * 1024 + threadIdx.x * 4;
    const int m0 = blockIdx.y * SROWS;
    if (threadIdx.x < SROWS * RDIM / 4)
        ((float4*)ds)[threadIdx.x] = ((const float4*)(D + (size_t)m0 * RDIM))[threadIdx.x];

    float cl = cvec[layer], ll = lvec[layer];
    float al = alpha_of(cl);
    float4 sg4 = sig4_from_spart(spart_sig, cnt, c, al, ll);
    float sg[4] = {sg4.x, sg4.y, sg4.z, sg4.w};
    float invsg[4] = {1.f / sg4.x, 1.f / sg4.y, 1.f / sg4.z, 1.f / sg4.w};

    float beta[4][16];
#pragma unroll
    for (int i = 0; i < 4; ++i)
#pragma unroll
        for (int q = 0; q < 4; ++q) {
            float4 t4 = ((const float4*)(B + (size_t)(c + i) * RDIM))[q];
            beta[i][q * 4 + 0] = t4.x; beta[i][q * 4 + 1] = t4.y;
            beta[i][q * 4 + 2] = t4.z; beta[i][q * 4 + 3] = t4.w;
        }
    __syncthreads();

    float tac[4][16];
#pragma unroll
    for (int i = 0; i < 4; ++i)
#pragma unroll
        for (int s = 0; s < 16; ++s) tac[i][s] = 0.f;

    for (int m = 0; m < SROWS; ++m) {
        float u[16];
#pragma unroll
        for (int q = 0; q < 4; ++q) {
            float4 u4 = ((const float4*)(ds + m * RDIM))[q];
            u[q * 4 + 0] = u4.x; u[q * 4 + 1] = u4.y;
            u[q * 4 + 2] = u4.z; u[q * 4 + 3] = u4.w;
        }
        float4 x4 = *(const float4*)(Xp + (size_t)(m0 + m) * DIM + c);
        float xv[4] = {x4.x, x4.y, x4.z, x4.w};
#pragma unroll
        for (int i = 0; i < 4; ++i) {
            float dot = 0.f;
#pragma unroll
            for (int s = 0; s < 16; ++s) dot += u[s] * beta[i][s];
            float res = (xv[i] != 0.f) ? (xv[i] - dot) : 0.f;
            float psi2 = fminf(fmaxf(res * invsg[i], -cl), cl);
            float coeff = psi2 * sg[i];
#pragma unroll
            for (int s = 0; s < 16; ++s) tac[i][s] += u[s] * coeff;
        }
    }
    float* tsl = tpart + (size_t)blockIdx.y * DIM * RDIM;
#pragma unroll
    for (int i = 0; i < 4; ++i)
#pragma unroll
        for (int q = 0; q < 4; ++q)
            *(float4*)(tsl + (size_t)(c + i) * RDIM + q * 4) =
                make_float4(tac[i][q * 4 + 0], tac[i][q * 4 + 1],
                            tac[i][q * 4 + 2], tac[i][q * 4 + 3]);
}

// ------- beta update: B += mu * Ainv @ (sum of tpart slices) ---------------
// block 256 thr (16 matrices), grid 256.
__global__ void __launch_bounds__(256) k_it_d(const float* __restrict__ Ainv,
                                              const float* __restrict__ tpart,
                                              const float* __restrict__ mvec, int layer,
                                              float* __restrict__ B) {
    __shared__ float t_sh[16][16];
    int c0 = blockIdx.x * 16;
    int cl_ = threadIdx.x >> 4;
    int s = threadIdx.x & 15;
    float tv = 0.f;
#pragma unroll 8
    for (int sl = 0; sl < NSL; ++sl)
        tv += tpart[((size_t)sl * DIM + c0 + cl_) * RDIM + s];
    t_sh[cl_][s] = tv;
    __syncthreads();

    int c = c0 + cl_;
    int j = s;
    float ml = mvec[layer];
    float d = 0.f;
#pragma unroll
    for (int q = 0; q < 4; ++q) {
        float4 a4 = *(const float4*)(Ainv + (size_t)c * 256 + j * 16 + q * 4);
        d += a4.x * t_sh[cl_][q * 4 + 0] + a4.y * t_sh[cl_][q * 4 + 1] +
             a4.z * t_sh[cl_][q * 4 + 2] + a4.w * t_sh[cl_][q * 4 + 3];
    }
    B[(size_t)c * RDIM + j] += ml * d;
}

// ---------------- final out = Uc @ Vtb^T -----------------------------------
__global__ void __launch_bounds__(256) k_out(const float* __restrict__ Uc,
                                             const float* __restrict__ Vtb,
                                             float* __restrict__ out) {
    __shared__ float us[64 * RDIM];
    int j = blockIdx.x * 256 + threadIdx.x;
    int i0 = blockIdx.y * 64;
    ((float4*)us)[threadIdx.x] = ((const float4*)(Uc + (size_t)i0 * RDIM))[threadIdx.x];
    float beta[16];
#pragma unroll
    for (int q = 0; q < 4; ++q) {
        float4 t4 = ((const float4*)(Vtb + (size_t)j * RDIM))[q];
        beta[q * 4 + 0] = t4.x; beta[q * 4 + 1] = t4.y;
        beta[q * 4 + 2] = t4.z; beta[q * 4 + 3] = t4.w;
    }
    __syncthreads();
#pragma unroll 4
    for (int r = 0; r < 64; ++r) {
        float dot = 0.f;
#pragma unroll
        for (int q = 0; q < 4; ++q) {
            float4 u4 = ((const float4*)(us + r * RDIM))[q];
            dot += u4.x * beta[q * 4 + 0] + u4.y * beta[q * 4 + 1] +
                   u4.z * beta[q * 4 + 2] + u4.w * beta[q * 4 + 3];
        }
        out[(size_t)(i0 + r) * DIM + j] = dot;
    }
}

extern "C" void kernel_launch(void* const* d_in, const int* in_sizes, int n_in,
                              void* d_out, int out_size, void* d_ws, size_t ws_size,
                              hipStream_t stream) {
    const float* U = (const float*)d_in[0];
    const float* V = (const float*)d_in[1];
    const float* X = (const float*)d_in[2];
    const float* cvec = (const float*)d_in[3];
    const float* lvec = (const float*)d_in[4];
    const float* mvec = (const float*)d_in[5];
    const float* sigma = (const float*)d_in[6];
    float* out = (float*)d_out;

    float* ws = (float*)d_ws;
    // BIG aliased region: Apart (buildA..invert) vs tpart+spartA+spartB (it-phase).
    // Apart = 16*4096*136 = 8,912,896 floats; tpart = 128*4096*16 = 8,388,608;
    // spartA @ +8,388,608 (512K); spartB @ +8,912,896 (512K) — no live overlap.
    float* big    = ws;
    float* tpart  = big;
    float* spartA = big + (size_t)NSL * DIM * RDIM;
    float* spartB = spartA + (size_t)NSL * DIM;
    float* Apart  = big;
    float* endbig = big + (size_t)NSL * DIM * RDIM + 2 * (size_t)NSL * DIM;
    float* Ainv   = endbig;                      // 4096*256
    float* cntc   = Ainv + (size_t)DIM * 256;    // 4096
    float* cntr   = cntc + DIM;                  // 4096
    float* Uc     = cntr + DIM;                  // 4096*16
    float* Vtb    = Uc + (size_t)DIM * RDIM;     // 4096*16
    float* Xt     = out;  // reuse d_out as transpose scratch until k_out

    // zero only the atomic targets (cntc, cntr — contiguous)
    hipMemsetAsync(cntc, 0, (size_t)2 * DIM * sizeof(float), stream);

    k_transpose<<<dim3(64, 64), 256, 0, stream>>>(X, Xt);
    k_init_uc<<<64, 256, 0, stream>>>(U, Uc);
    k_init_vt<<<16, 256, 0, stream>>>(V, Vtb);
    k_count<<<dim3(16, 16), 256, 0, stream>>>(X, cntc);
    k_count<<<dim3(16, 16), 256, 0, stream>>>(Xt, cntr);

    for (int layer = 0; layer < 3; ++layer) {
        // ---- V step: columns of X, design rows = Uc, beta rows = Vtb ----
        k_buildA<<<dim3(64, NCHUNK), 256, 0, stream>>>(X, Uc, Apart);
        k_invert<<<512, 128, 0, stream>>>(Apart, Ainv);
        k_it_a<<<dim3(4, NSL), 256, 0, stream>>>(X, Uc, Vtb, spartA, sigma, cntc,
                                                 cvec, lvec, layer, 1, spartA);
        k_it_c<<<dim3(4, NSL), 256, 0, stream>>>(X, Uc, Vtb, spartA, cntc,
                                                 cvec, lvec, layer, tpart);
        k_it_d<<<256, 256, 0, stream>>>(Ainv, tpart, mvec, layer, Vtb);
        k_it_a<<<dim3(4, NSL), 256, 0, stream>>>(X, Uc, Vtb, spartA, sigma, cntc,
                                                 cvec, lvec, layer, 0, spartB);
        k_it_c<<<dim3(4, NSL), 256, 0, stream>>>(X, Uc, Vtb, spartB, cntc,
                                                 cvec, lvec, layer, tpart);
        k_it_d<<<256, 256, 0, stream>>>(Ainv, tpart, mvec, layer, Vtb);

        // ---- U step: columns of Xt, design rows = Vtb, beta rows = Uc ----
        k_buildA<<<dim3(64, NCHUNK), 256, 0, stream>>>(Xt, Vtb, Apart);
        k_invert<<<512, 128, 0, stream>>>(Apart, Ainv);
        k_it_a<<<dim3(4, NSL), 256, 0, stream>>>(Xt, Vtb, Uc, spartA, sigma, cntr,
                                                 cvec, lvec, layer, 1, spartA);
        k_it_c<<<dim3(4, NSL), 256, 0, stream>>>(Xt, Vtb, Uc, spartA, cntr,
                                                 cvec, lvec, layer, tpart);
        k_it_d<<<256, 256, 0, stream>>>(Ainv, tpart, mvec, layer, Uc);
        k_it_a<<<dim3(4, NSL), 256, 0, stream>>>(Xt, Vtb, Uc, spartA, sigma, cntr,
                                                 cvec, lvec, layer, 0, spartB);
        k_it_c<<<dim3(4, NSL), 256, 0, stream>>>(Xt, Vtb, Uc, spartB, cntr,
                                                 cvec, lvec, layer, tpart);
        k_it_d<<<256, 256, 0, stream>>>(Ainv, tpart, mvec, layer, Uc);
    }
    k_out<<<dim3(16, 64), 256, 0, stream>>>(Uc, Vtb, out);
}